// Round 3
// baseline (578.272 us; speedup 1.0000x reference)
//
#include <hip/hip_runtime.h>

#define B_ 1024
#define N_ 30
#define P_ 16
#define NR_ 870
#define DR_ 3
#define DE_ 5
#define DO_ 6
#define NT_ 5

typedef unsigned short ushort_t;
typedef __attribute__((ext_vector_type(8))) short short8_t;
typedef __attribute__((ext_vector_type(4))) float f32x4;

union Frag { short8_t v; ushort_t u[8]; unsigned int d[4]; };

__device__ __forceinline__ float bf2f(ushort_t u) {
    union { unsigned int i; float f; } v; v.i = ((unsigned int)u) << 16; return v.f;
}
__device__ __forceinline__ ushort_t f2bf(float f) {
    union { float f; unsigned int i; } v; v.f = f;
    unsigned int x = v.i;
    return (ushort_t)((x + 0x7FFFu + ((x >> 16) & 1u)) >> 16);
}
__device__ __forceinline__ void split(float v, ushort_t& h, ushort_t& l) {
    h = f2bf(v);
    float r = v - bf2f(h);      // exact (Sterbenz)
    l = f2bf(r);
}
// packed hi/lo split: 2 values -> (hi dword, lo dword), RNE, ~6 VALU ops
__device__ __forceinline__ unsigned int cvtpk(float a, float b) {
    unsigned int r;
    asm("v_cvt_pk_bf16_f32 %0, %1, %2" : "=v"(r) : "v"(a), "v"(b));
    return r;
}
__device__ __forceinline__ void split2(float a, float b,
                                       unsigned int& h, unsigned int& l) {
    h = cvtpk(a, b);
    union { unsigned int i; float f; } x0, x1;
    x0.i = h << 16; x1.i = h & 0xFFFF0000u;
    l = cvtpk(a - x0.f, b - x1.f);
}
__device__ __forceinline__ f32x4 mfma(short8_t a, short8_t b, f32x4 c) {
    return __builtin_amdgcn_mfma_f32_16x16x32_bf16(a, b, c, 0, 0, 0);
}

// ---------------------------------------------------------------------------
// k_prep: pack weights & x into MFMA A-fragment layout (bf16 hi/lo split).
// ---------------------------------------------------------------------------
__global__ __launch_bounds__(256) void k_prep(
    const float* __restrict__ x,  const float* __restrict__ w1,
    const float* __restrict__ w2, const float* __restrict__ wo1,
    const float* __restrict__ wo2,
    ushort_t* __restrict__ xAh,  ushort_t* __restrict__ xAl,
    ushort_t* __restrict__ w1h,  ushort_t* __restrict__ w1l,
    ushort_t* __restrict__ w2h,  ushort_t* __restrict__ w2l,
    ushort_t* __restrict__ wo1h, ushort_t* __restrict__ wo1l,
    ushort_t* __restrict__ wo2h, ushort_t* __restrict__ wo2l)
{
    const int blk = blockIdx.x, tid = threadIdx.x;
    if (blk < 1024) {                       // xA: A[m=p][k=n], per batch, 1 frag
        int b = blk;
        for (int idx = tid; idx < 512; idx += 256) {
            int lane = idx >> 3, j = idx & 7;
            int p = lane & 15, n = (lane >> 4) * 8 + j;
            float v = (n < N_) ? x[(b * N_ + n) * P_ + p] : 0.f;
            ushort_t h_, l_; split(v, h_, l_);
            xAh[b * 512 + idx] = h_; xAl[b * 512 + idx] = l_;
        }
    } else if (blk == 1024) {               // w1: 8 mt x 2 kt (kt=1 unused now)
        for (int idx = tid; idx < 16 * 512; idx += 256) {
            int f = idx >> 9, eps = idx & 511;
            int lane = eps >> 3, j = eps & 7;
            int mt = f >> 1, kt = f & 1;
            int m = mt * 16 + (lane & 15);
            int k = kt * 32 + (lane >> 4) * 8 + j;
            float v = (k < 35) ? w1[m * 35 + k] : 0.f;
            ushort_t h_, l_; split(v, h_, l_);
            w1h[idx] = h_; w1l[idx] = l_;
        }
    } else if (blk == 1025) {               // w2: 4 mt x 4 kt
        for (int idx = tid; idx < 16 * 512; idx += 256) {
            int f = idx >> 9, eps = idx & 511;
            int lane = eps >> 3, j = eps & 7;
            int mt = f >> 2, kt = f & 3;
            int m = mt * 16 + (lane & 15);
            int k = kt * 32 + (lane >> 4) * 8 + j;
            float v = w2[m * 128 + k];
            ushort_t h_, l_; split(v, h_, l_);
            w2h[idx] = h_; w2l[idx] = l_;
        }
    } else if (blk == 1026) {               // wo1: 8 mt x 1 kt, K pad 21->32
        for (int idx = tid; idx < 8 * 512; idx += 256) {
            int f = idx >> 9, eps = idx & 511;
            int lane = eps >> 3, j = eps & 7;
            int m = f * 16 + (lane & 15);
            int k = (lane >> 4) * 8 + j;
            float v = (k < 21) ? wo1[m * 21 + k] : 0.f;
            ushort_t h_, l_; split(v, h_, l_);
            wo1h[idx] = h_; wo1l[idx] = l_;
        }
    } else {                                // wo2: 4 mt x 4 kt
        for (int idx = tid; idx < 16 * 512; idx += 256) {
            int f = idx >> 9, eps = idx & 511;
            int lane = eps >> 3, j = eps & 7;
            int mt = f >> 2, kt = f & 3;
            int m = mt * 16 + (lane & 15);
            int k = kt * 32 + (lane >> 4) * 8 + j;
            float v = wo2[m * 128 + k];
            ushort_t h_, l_; split(v, h_, l_);
            wo2h[idx] = h_; wo2l[idx] = l_;
        }
    }
}

// ---------------------------------------------------------------------------
// k_edge v5: 64 edges/block, LDS 32.0 KB -> 5 blocks/CU.
//  - RA contribution moved out of MFMA into exact-fp32 VALU epilogue of fr1:
//    aT shrinks to K=32 (Orr|Ors only), fr1 kt=1 tile gone (24 fewer MFMAs/wave).
//  - h2T aliases h1T (extra barrier S5b); raT stages RA in f32.
// ---------------------------------------------------------------------------
__global__ __launch_bounds__(256, 5) void k_edge(
    const float* __restrict__ RR, const float* __restrict__ RS,
    const float* __restrict__ RA, const float* __restrict__ w1f,
    const float* __restrict__ b1, const float* __restrict__ b2,
    const float* __restrict__ w3, const float* __restrict__ b3,
    const ushort_t* __restrict__ xAh, const ushort_t* __restrict__ xAl,
    const ushort_t* __restrict__ w1h, const ushort_t* __restrict__ w1l,
    const ushort_t* __restrict__ w2h, const ushort_t* __restrict__ w2l,
    float* __restrict__ Ebar)
{
    const int b   = blockIdx.y;
    const int r0  = blockIdx.x * 64;
    const int tid = threadIdx.x;
    const int lane = tid & 63;
    const int wv   = tid >> 6;          // wave 0..3
    const int l15  = lane & 15;
    const int q    = lane >> 4;         // quad 0..3

    __shared__ ushort_t aT[2][64][40];  // 10240 B  [hi/lo][e][k 0..31 = Orr|Ors]
    __shared__ union {                  // 18432 B
        ushort_t h1T[2][64][72];
        float    h2T[64][68];
    } u2;
    __shared__ float Ee[64][6];         // 1536 B
    __shared__ float raT[64][4];        // 1024 B (RA f32, cols 0..2)
    __shared__ float b1s[128], b2s[64]; // 768 B

    if (tid < 128) b1s[tid] = b1[tid];
    if (tid < 64)  b2s[tid] = b2[tid];

    const int eloc = wv * 16 + l15;
    const int r = r0 + eloc;
    const bool rvalid = (r < NR_);
    const int rc = rvalid ? r : NR_ - 1;      // clamped (invalid rows zeroed at fr3)

    // ---- phase A: Orr/Ors via MFMA; wave wv owns e-tile wv ----
    {
        Frag xh, xl;
        xh.v = ((const short8_t*)xAh)[b * 64 + lane];
        xl.v = ((const short8_t*)xAl)[b * 64 + lane];

        float vr[8], vs[8];
        #pragma unroll
        for (int j = 0; j < 8; ++j) {
            int n = q * 8 + j;
            vr[j] = (n < N_) ? RR[(b * N_ + n) * NR_ + rc] : 0.f;
            vs[j] = (n < N_) ? RS[(b * N_ + n) * NR_ + rc] : 0.f;
        }
        Frag rrh, rrl, rsh, rsl;
        #pragma unroll
        for (int d0 = 0; d0 < 4; ++d0) {
            split2(vr[2*d0], vr[2*d0+1], rrh.d[d0], rrl.d[d0]);
            split2(vs[2*d0], vs[2*d0+1], rsh.d[d0], rsl.d[d0]);
        }

        f32x4 aR = {0.f,0.f,0.f,0.f}, aS = {0.f,0.f,0.f,0.f};
        aR = mfma(xh.v, rrh.v, aR); aR = mfma(xl.v, rrh.v, aR); aR = mfma(xh.v, rrl.v, aR);
        aS = mfma(xh.v, rsh.v, aS); aS = mfma(xl.v, rsh.v, aS); aS = mfma(xh.v, rsl.v, aS);

        unsigned int h01, h23, l01, l23;
        split2(aR[0], aR[1], h01, l01); split2(aR[2], aR[3], h23, l23);
        { uint2 hh = {h01, h23}, ll = {l01, l23};
          *(uint2*)&aT[0][eloc][q * 4] = hh;
          *(uint2*)&aT[1][eloc][q * 4] = ll; }
        split2(aS[0], aS[1], h01, l01); split2(aS[2], aS[3], h23, l23);
        { uint2 hh = {h01, h23}, ll = {l01, l23};
          *(uint2*)&aT[0][eloc][16 + q * 4] = hh;
          *(uint2*)&aT[1][eloc][16 + q * 4] = ll; }

        if (q < DR_)
            raT[eloc][q] = rvalid ? RA[(b * DR_ + q) * NR_ + r] : 0.f;
    }
    __syncthreads();                                      // S2

    // ---- fr1/fr2 halves: fr1 half hf -> h1T; fr2 partial into registers ----
    short8_t W2hf[4], W2lf[4];
    #pragma unroll
    for (int kt = 0; kt < 4; ++kt) {
        W2hf[kt] = ((const short8_t*)w2h)[(wv * 4 + kt) * 64 + lane];
        W2lf[kt] = ((const short8_t*)w2l)[(wv * 4 + kt) * 64 + lane];
    }
    f32x4 acc2[4];
    #pragma unroll
    for (int et = 0; et < 4; ++et) acc2[et] = (f32x4){0.f,0.f,0.f,0.f};

    #pragma unroll
    for (int hf = 0; hf < 2; ++hf) {
        // fr1: wave owns mt = hf*4 + wv; K-tile kt=0 only; RA part in f32 VALU
        {
            const int mt = hf * 4 + wv;
            short8_t W1h0 = ((const short8_t*)w1h)[(mt * 2 + 0) * 64 + lane];
            short8_t W1l0 = ((const short8_t*)w1l)[(mt * 2 + 0) * 64 + lane];
            float w1c[4][3];
            #pragma unroll
            for (int c = 0; c < 4; ++c) {
                int row = mt * 16 + q * 4 + c;
                w1c[c][0] = w1f[row * 35 + 32];
                w1c[c][1] = w1f[row * 35 + 33];
                w1c[c][2] = w1f[row * 35 + 34];
            }
            #pragma unroll
            for (int et = 0; et < 4; ++et) {
                int e = et * 16 + l15;
                f32x4 acc = {0.f,0.f,0.f,0.f};
                short8_t Bh = *(const short8_t*)&aT[0][e][q * 8];
                short8_t Bl = *(const short8_t*)&aT[1][e][q * 8];
                acc = mfma(W1h0, Bh, acc);
                acc = mfma(W1l0, Bh, acc);
                acc = mfma(W1h0, Bl, acc);
                float ra0 = raT[e][0], ra1 = raT[e][1], ra2 = raT[e][2];
                float hv0 = fmaxf(acc[0] + b1s[mt*16 + q*4 + 0]
                                  + w1c[0][0]*ra0 + w1c[0][1]*ra1 + w1c[0][2]*ra2, 0.f);
                float hv1 = fmaxf(acc[1] + b1s[mt*16 + q*4 + 1]
                                  + w1c[1][0]*ra0 + w1c[1][1]*ra1 + w1c[1][2]*ra2, 0.f);
                float hv2 = fmaxf(acc[2] + b1s[mt*16 + q*4 + 2]
                                  + w1c[2][0]*ra0 + w1c[2][1]*ra1 + w1c[2][2]*ra2, 0.f);
                float hv3 = fmaxf(acc[3] + b1s[mt*16 + q*4 + 3]
                                  + w1c[3][0]*ra0 + w1c[3][1]*ra1 + w1c[3][2]*ra2, 0.f);
                unsigned int d01, d23, e01, e23;
                split2(hv0, hv1, d01, e01); split2(hv2, hv3, d23, e23);
                uint2 hh = {d01, d23}, ll = {e01, e23};
                *(uint2*)&u2.h1T[0][e][wv * 16 + q * 4] = hh;
                *(uint2*)&u2.h1T[1][e][wv * 16 + q * 4] = ll;
            }
        }
        __syncthreads();                                  // S3 / S5

        // fr2 partial: K-tiles kt = hf*2 + {0,1}
        #pragma unroll
        for (int et = 0; et < 4; ++et) {
            int e = et * 16 + l15;
            #pragma unroll
            for (int ktl = 0; ktl < 2; ++ktl) {
                short8_t bh = *(const short8_t*)&u2.h1T[0][e][ktl * 32 + q * 8];
                short8_t bl = *(const short8_t*)&u2.h1T[1][e][ktl * 32 + q * 8];
                acc2[et] = mfma(W2hf[hf * 2 + ktl], bh, acc2[et]);
                acc2[et] = mfma(W2lf[hf * 2 + ktl], bh, acc2[et]);
                acc2[et] = mfma(W2hf[hf * 2 + ktl], bl, acc2[et]);
            }
        }
        if (hf == 1) {
            __syncthreads();                              // S5b (h1T dead -> h2T)
            #pragma unroll
            for (int et = 0; et < 4; ++et) {
                int e = et * 16 + l15;
                float4 st;
                st.x = fmaxf(acc2[et][0] + b2s[wv * 16 + q * 4 + 0], 0.f);
                st.y = fmaxf(acc2[et][1] + b2s[wv * 16 + q * 4 + 1], 0.f);
                st.z = fmaxf(acc2[et][2] + b2s[wv * 16 + q * 4 + 2], 0.f);
                st.w = fmaxf(acc2[et][3] + b2s[wv * 16 + q * 4 + 3], 0.f);
                *(float4*)&u2.h2T[e][wv * 16 + q * 4] = st;
            }
        }
        __syncthreads();                                  // S4 / S6
    }

    // ---- fr3 (64 -> 5), VALU; w3/b3 from global (L2-hot) ----
    for (int it = tid; it < 64 * DE_; it += 256) {
        int e = it / DE_, i = it - e * DE_;
        float s = b3[i];
        const float* wr = w3 + i * 64;
        #pragma unroll
        for (int k = 0; k < 64; k += 4) {
            float4 hv = *(const float4*)&u2.h2T[e][k];
            float4 wv4 = *(const float4*)&wr[k];
            s += hv.x * wv4.x + hv.y * wv4.y + hv.z * wv4.z + hv.w * wv4.w;
        }
        Ee[e][i] = ((r0 + e) < NR_) ? fmaxf(s, 0.f) : 0.f;
    }
    __syncthreads();                                      // S7

    // ---- Ebar[b][i][n] += sum_e Ee[e][i] * RR[n][r0+e] (RR L2-hot) ----
    if (tid < DE_ * N_) {
        int i = tid / N_, n = tid - i * N_;
        const float* pr = &RR[(b * N_ + n) * NR_ + r0];
        const int emax = (NR_ - r0 < 64) ? (NR_ - r0) : 64;
        float s = 0.f;
        for (int e = 0; e < emax; ++e) s += Ee[e][i] * pr[e];
        atomicAdd(&Ebar[(b * DE_ + i) * N_ + n], s);
    }
}

// ---------------------------------------------------------------------------
// k_nodef v2: fused node+final MLP, 1 batch/block (1024 blocks), LDS 32.0 KB
//   -> 5 blocks/CU, 4 dispatch rounds (was 2 blocks/CU, 1 round).
// ---------------------------------------------------------------------------
__global__ __launch_bounds__(256, 5) void k_nodef(
    const float* __restrict__ x, const float* __restrict__ Ebar,
    const float* __restrict__ bo1, const float* __restrict__ bo2,
    const float* __restrict__ wo3, const float* __restrict__ bo3,
    const ushort_t* __restrict__ wo1h, const ushort_t* __restrict__ wo1l,
    const ushort_t* __restrict__ wo2h, const ushort_t* __restrict__ wo2l,
    const float* __restrict__ wc1, const float* __restrict__ bc1,
    const float* __restrict__ wc2, const float* __restrict__ bc2,
    const float* __restrict__ wc3, const float* __restrict__ bc3,
    float* __restrict__ out)
{
    const int b = blockIdx.x;
    const int tid = threadIdx.x;
    const int lane = tid & 63;
    const int wv = tid >> 6;
    const int l15 = lane & 15;
    const int q = lane >> 4;

    __shared__ union {                      // 5120 B (cT dead before f used)
        ushort_t cT[2][32][40];
        struct { float fs[192]; float h1s[128]; float h2s[64]; } f;
    } u;
    __shared__ ushort_t h1T[2][32][136];    // 17408 B
    __shared__ float h2T[32][68];           // 8704 B
    __shared__ float b1s[128], b2s[64];     // 768 B

    if (tid < 128) b1s[tid] = bo1[tid];
    if (tid < 64)  b2s[tid] = bo2[tid];

    for (int idx = tid; idx < 32 * 32; idx += 256) {
        int c = idx >> 5, k = idx & 31;
        float v = 0.f;
        if (c < N_) {
            if (k < 16)      v = x[(b * N_ + c) * P_ + k];
            else if (k < 21) v = Ebar[(b * DE_ + (k - 16)) * N_ + c];
        }
        ushort_t h_, l_; split(v, h_, l_);
        u.cT[0][c][k] = h_; u.cT[1][c][k] = l_;
    }
    __syncthreads();

    {   // fo1: wave wv owns mt in {wv, wv+4}; 2 et tiles
        short8_t Wh[2], Wl[2];
        #pragma unroll
        for (int mi = 0; mi < 2; ++mi) {
            int mt = wv + mi * 4;
            Wh[mi] = ((const short8_t*)wo1h)[mt * 64 + lane];
            Wl[mi] = ((const short8_t*)wo1l)[mt * 64 + lane];
        }
        #pragma unroll
        for (int et = 0; et < 2; ++et) {
            int c = et * 16 + l15;
            short8_t bh = *(const short8_t*)&u.cT[0][c][q * 8];
            short8_t bl = *(const short8_t*)&u.cT[1][c][q * 8];
            #pragma unroll
            for (int mi = 0; mi < 2; ++mi) {
                int mt = wv + mi * 4;
                f32x4 acc = {0.f,0.f,0.f,0.f};
                acc = mfma(Wh[mi], bh, acc);
                acc = mfma(Wl[mi], bh, acc);
                acc = mfma(Wh[mi], bl, acc);
                float hv0 = fmaxf(acc[0] + b1s[mt * 16 + q * 4 + 0], 0.f);
                float hv1 = fmaxf(acc[1] + b1s[mt * 16 + q * 4 + 1], 0.f);
                float hv2 = fmaxf(acc[2] + b1s[mt * 16 + q * 4 + 2], 0.f);
                float hv3 = fmaxf(acc[3] + b1s[mt * 16 + q * 4 + 3], 0.f);
                unsigned int d01, d23, e01, e23;
                split2(hv0, hv1, d01, e01); split2(hv2, hv3, d23, e23);
                uint2 hh = {d01, d23}, ll = {e01, e23};
                *(uint2*)&h1T[0][c][mt * 16 + q * 4] = hh;
                *(uint2*)&h1T[1][c][mt * 16 + q * 4] = ll;
            }
        }
    }
    __syncthreads();

    {   // fo2: wave wv owns rows wv*16..wv*16+15, K=128 (4 kt)
        short8_t Wh[4], Wl[4];
        #pragma unroll
        for (int kt = 0; kt < 4; ++kt) {
            Wh[kt] = ((const short8_t*)wo2h)[(wv * 4 + kt) * 64 + lane];
            Wl[kt] = ((const short8_t*)wo2l)[(wv * 4 + kt) * 64 + lane];
        }
        #pragma unroll
        for (int et = 0; et < 2; ++et) {
            int c = et * 16 + l15;
            f32x4 acc = {0.f,0.f,0.f,0.f};
            #pragma unroll
            for (int kt = 0; kt < 4; ++kt) {
                short8_t bh = *(const short8_t*)&h1T[0][c][kt * 32 + q * 8];
                short8_t bl = *(const short8_t*)&h1T[1][c][kt * 32 + q * 8];
                acc = mfma(Wh[kt], bh, acc);
                acc = mfma(Wl[kt], bh, acc);
                acc = mfma(Wh[kt], bl, acc);
            }
            float4 st;
            st.x = fmaxf(acc[0] + b2s[wv * 16 + q * 4 + 0], 0.f);
            st.y = fmaxf(acc[1] + b2s[wv * 16 + q * 4 + 1], 0.f);
            st.z = fmaxf(acc[2] + b2s[wv * 16 + q * 4 + 2], 0.f);
            st.w = fmaxf(acc[3] + b2s[wv * 16 + q * 4 + 3], 0.f);
            *(float4*)&h2T[c][wv * 16 + q * 4] = st;
        }
    }
    __syncthreads();

    // fo3 -> fs (cT dead; union reuse)
    if (tid < N_ * DO_ + 12) {   // 192 threads
        int c = tid / DO_, i = tid - c * DO_;
        if (c < N_) {
            float s = bo3[i];
            const float* wr = wo3 + i * 64;
            #pragma unroll
            for (int k = 0; k < 64; k += 4) {
                float4 hv = *(const float4*)&h2T[c][k];
                float4 wv4 = *(const float4*)&wr[k];
                s += hv.x * wv4.x + hv.y * wv4.y + hv.z * wv4.z + hv.w * wv4.w;
            }
            u.f.fs[c * DO_ + i] = fmaxf(s, 0.f);
        }
    }
    __syncthreads();

    // ---- final MLP (fp32 VALU) ----
    if (tid < 128) {
        const float* wr = wc1 + tid * 180;
        float s = bc1[tid];
        #pragma unroll 5
        for (int k = 0; k < 180; k += 4) {
            float4 wv4 = *(const float4*)&wr[k];
            s += u.f.fs[k] * wv4.x + u.f.fs[k + 1] * wv4.y
               + u.f.fs[k + 2] * wv4.z + u.f.fs[k + 3] * wv4.w;
        }
        u.f.h1s[tid] = fmaxf(s, 0.f);
    }
    __syncthreads();

    if (tid < 64) {
        const float* wr = wc2 + tid * 128;
        float s = bc2[tid];
        #pragma unroll 4
        for (int k = 0; k < 128; k += 4) {
            float4 wv4 = *(const float4*)&wr[k];
            s += u.f.h1s[k] * wv4.x + u.f.h1s[k + 1] * wv4.y
               + u.f.h1s[k + 2] * wv4.z + u.f.h1s[k + 3] * wv4.w;
        }
        u.f.h2s[tid] = fmaxf(s, 0.f);
    }
    __syncthreads();

    if (tid < NT_) {
        const float* wr = wc3 + tid * 64;
        float s = bc3[tid];
        #pragma unroll
        for (int k = 0; k < 64; k += 4) {
            float4 wv4 = *(const float4*)&wr[k];
            s += u.f.h2s[k] * wv4.x + u.f.h2s[k + 1] * wv4.y
               + u.f.h2s[k + 2] * wv4.z + u.f.h2s[k + 3] * wv4.w;
        }
        out[b * NT_ + tid] = s;
    }
}

extern "C" void kernel_launch(void* const* d_in, const int* in_sizes, int n_in,
                              void* d_out, int out_size, void* d_ws, size_t ws_size,
                              hipStream_t stream)
{
    const float* x    = (const float*)d_in[0];
    const float* RR   = (const float*)d_in[1];
    const float* RS   = (const float*)d_in[2];
    const float* RA   = (const float*)d_in[3];
    const float* fr1w = (const float*)d_in[4];
    const float* fr1b = (const float*)d_in[5];
    const float* fr2w = (const float*)d_in[6];
    const float* fr2b = (const float*)d_in[7];
    const float* fr3w = (const float*)d_in[8];
    const float* fr3b = (const float*)d_in[9];
    const float* fo1w = (const float*)d_in[10];
    const float* fo1b = (const float*)d_in[11];
    const float* fo2w = (const float*)d_in[12];
    const float* fo2b = (const float*)d_in[13];
    const float* fo3w = (const float*)d_in[14];
    const float* fo3b = (const float*)d_in[15];
    const float* fc1w = (const float*)d_in[16];
    const float* fc1b = (const float*)d_in[17];
    const float* fc2w = (const float*)d_in[18];
    const float* fc2b = (const float*)d_in[19];
    const float* fc3w = (const float*)d_in[20];
    const float* fc3b = (const float*)d_in[21];
    float* out = (float*)d_out;

    // ---- workspace map ----
    float* Ebar = (float*)d_ws;                       // 1024*5*30
    ushort_t* base = (ushort_t*)(Ebar + B_ * DE_ * N_);
    ushort_t* xAh  = base;             ushort_t* xAl  = xAh  + 1024 * 512;
    ushort_t* w1h  = xAl  + 1024*512;  ushort_t* w1l  = w1h  + 16 * 512;
    ushort_t* w2h  = w1l  + 16*512;    ushort_t* w2l  = w2h  + 16 * 512;
    ushort_t* wo1h = w2l  + 16*512;    ushort_t* wo1l = wo1h + 8 * 512;
    ushort_t* wo2h = wo1l + 8*512;     ushort_t* wo2l = wo2h + 16 * 512;

    hipMemsetAsync(Ebar, 0, (size_t)B_ * DE_ * N_ * sizeof(float), stream);

    k_prep<<<1028, 256, 0, stream>>>(x, fr1w, fr2w, fo1w, fo2w,
                                     xAh, xAl, w1h, w1l, w2h, w2l,
                                     wo1h, wo1l, wo2h, wo2l);

    dim3 g1(14, B_);   // 14 * 64 = 896 >= 870 edges
    k_edge<<<g1, 256, 0, stream>>>(RR, RS, RA, fr1w, fr1b, fr2b, fr3w, fr3b,
                                   xAh, xAl, w1h, w1l, w2h, w2l, Ebar);
    k_nodef<<<B_, 256, 0, stream>>>(x, Ebar, fo1b, fo2b, fo3w, fo3b,
                                    wo1h, wo1l, wo2h, wo2l,
                                    fc1w, fc1b, fc2w, fc2b, fc3w, fc3b, out);
}

// Round 4
// 548.896 us; speedup vs baseline: 1.0535x; 1.0535x over previous
//
#include <hip/hip_runtime.h>

#define B_ 1024
#define N_ 30
#define P_ 16
#define NR_ 870
#define DR_ 3
#define DE_ 5
#define DO_ 6
#define NT_ 5

typedef unsigned short ushort_t;
typedef __attribute__((ext_vector_type(8))) short short8_t;
typedef __attribute__((ext_vector_type(4))) float f32x4;

union Frag { short8_t v; ushort_t u[8]; unsigned int d[4]; };

__device__ __forceinline__ float bf2f(ushort_t u) {
    union { unsigned int i; float f; } v; v.i = ((unsigned int)u) << 16; return v.f;
}
__device__ __forceinline__ ushort_t f2bf(float f) {
    union { float f; unsigned int i; } v; v.f = f;
    unsigned int x = v.i;
    return (ushort_t)((x + 0x7FFFu + ((x >> 16) & 1u)) >> 16);
}
__device__ __forceinline__ void split(float v, ushort_t& h, ushort_t& l) {
    h = f2bf(v);
    float r = v - bf2f(h);      // exact (Sterbenz)
    l = f2bf(r);
}
// packed hi/lo split: 2 values -> (hi dword, lo dword), RNE, ~6 VALU ops
__device__ __forceinline__ unsigned int cvtpk(float a, float b) {
    unsigned int r;
    asm("v_cvt_pk_bf16_f32 %0, %1, %2" : "=v"(r) : "v"(a), "v"(b));
    return r;
}
__device__ __forceinline__ void split2(float a, float b,
                                       unsigned int& h, unsigned int& l) {
    h = cvtpk(a, b);
    union { unsigned int i; float f; } x0, x1;
    x0.i = h << 16; x1.i = h & 0xFFFF0000u;
    l = cvtpk(a - x0.f, b - x1.f);
}
__device__ __forceinline__ f32x4 mfma(short8_t a, short8_t b, f32x4 c) {
    return __builtin_amdgcn_mfma_f32_16x16x32_bf16(a, b, c, 0, 0, 0);
}

// ---------------------------------------------------------------------------
// k_prep: pack weights & x into MFMA A-fragment layout (bf16 hi/lo split).
// ---------------------------------------------------------------------------
__global__ __launch_bounds__(256) void k_prep(
    const float* __restrict__ x,  const float* __restrict__ w1,
    const float* __restrict__ w2, const float* __restrict__ wo1,
    const float* __restrict__ wo2,
    ushort_t* __restrict__ xAh,  ushort_t* __restrict__ xAl,
    ushort_t* __restrict__ w1h,  ushort_t* __restrict__ w1l,
    ushort_t* __restrict__ w2h,  ushort_t* __restrict__ w2l,
    ushort_t* __restrict__ wo1h, ushort_t* __restrict__ wo1l,
    ushort_t* __restrict__ wo2h, ushort_t* __restrict__ wo2l)
{
    const int blk = blockIdx.x, tid = threadIdx.x;
    if (blk < 1024) {                       // xA: A[m=p][k=n], per batch, 1 frag
        int b = blk;
        for (int idx = tid; idx < 512; idx += 256) {
            int lane = idx >> 3, j = idx & 7;
            int p = lane & 15, n = (lane >> 4) * 8 + j;
            float v = (n < N_) ? x[(b * N_ + n) * P_ + p] : 0.f;
            ushort_t h_, l_; split(v, h_, l_);
            xAh[b * 512 + idx] = h_; xAl[b * 512 + idx] = l_;
        }
    } else if (blk == 1024) {               // w1: 8 mt x 2 kt (kt=1 unused now)
        for (int idx = tid; idx < 16 * 512; idx += 256) {
            int f = idx >> 9, eps = idx & 511;
            int lane = eps >> 3, j = eps & 7;
            int mt = f >> 1, kt = f & 1;
            int m = mt * 16 + (lane & 15);
            int k = kt * 32 + (lane >> 4) * 8 + j;
            float v = (k < 35) ? w1[m * 35 + k] : 0.f;
            ushort_t h_, l_; split(v, h_, l_);
            w1h[idx] = h_; w1l[idx] = l_;
        }
    } else if (blk == 1025) {               // w2: 4 mt x 4 kt
        for (int idx = tid; idx < 16 * 512; idx += 256) {
            int f = idx >> 9, eps = idx & 511;
            int lane = eps >> 3, j = eps & 7;
            int mt = f >> 2, kt = f & 3;
            int m = mt * 16 + (lane & 15);
            int k = kt * 32 + (lane >> 4) * 8 + j;
            float v = w2[m * 128 + k];
            ushort_t h_, l_; split(v, h_, l_);
            w2h[idx] = h_; w2l[idx] = l_;
        }
    } else if (blk == 1026) {               // wo1: 8 mt x 1 kt, K pad 21->32
        for (int idx = tid; idx < 8 * 512; idx += 256) {
            int f = idx >> 9, eps = idx & 511;
            int lane = eps >> 3, j = eps & 7;
            int m = f * 16 + (lane & 15);
            int k = (lane >> 4) * 8 + j;
            float v = (k < 21) ? wo1[m * 21 + k] : 0.f;
            ushort_t h_, l_; split(v, h_, l_);
            wo1h[idx] = h_; wo1l[idx] = l_;
        }
    } else {                                // wo2: 4 mt x 4 kt
        for (int idx = tid; idx < 16 * 512; idx += 256) {
            int f = idx >> 9, eps = idx & 511;
            int lane = eps >> 3, j = eps & 7;
            int mt = f >> 2, kt = f & 3;
            int m = mt * 16 + (lane & 15);
            int k = kt * 32 + (lane >> 4) * 8 + j;
            float v = wo2[m * 128 + k];
            ushort_t h_, l_; split(v, h_, l_);
            wo2h[idx] = h_; wo2l[idx] = l_;
        }
    }
}

// ---------------------------------------------------------------------------
// k_edge v5b: 64 edges/block, LDS 32.0 KB (5 blocks/CU possible).
//  - RA contribution in exact-fp32 VALU epilogue of fr1 (aT is K=32 only).
//  - NO register-count clamp: __launch_bounds__(256,5) in v5 forced 48 VGPR
//    and spilled 350 MB to scratch (round-3 counters). Plain bounds here.
// ---------------------------------------------------------------------------
__global__ __launch_bounds__(256) void k_edge(
    const float* __restrict__ RR, const float* __restrict__ RS,
    const float* __restrict__ RA, const float* __restrict__ w1f,
    const float* __restrict__ b1, const float* __restrict__ b2,
    const float* __restrict__ w3, const float* __restrict__ b3,
    const ushort_t* __restrict__ xAh, const ushort_t* __restrict__ xAl,
    const ushort_t* __restrict__ w1h, const ushort_t* __restrict__ w1l,
    const ushort_t* __restrict__ w2h, const ushort_t* __restrict__ w2l,
    float* __restrict__ Ebar)
{
    const int b   = blockIdx.y;
    const int r0  = blockIdx.x * 64;
    const int tid = threadIdx.x;
    const int lane = tid & 63;
    const int wv   = tid >> 6;          // wave 0..3
    const int l15  = lane & 15;
    const int q    = lane >> 4;         // quad 0..3

    __shared__ ushort_t aT[2][64][40];  // 10240 B  [hi/lo][e][k 0..31 = Orr|Ors]
    __shared__ union {                  // 18432 B
        ushort_t h1T[2][64][72];
        float    h2T[64][68];
    } u2;
    __shared__ float Ee[64][6];         // 1536 B
    __shared__ float raT[64][4];        // 1024 B (RA f32, cols 0..2)
    __shared__ float b1s[128], b2s[64]; // 768 B

    if (tid < 128) b1s[tid] = b1[tid];
    if (tid < 64)  b2s[tid] = b2[tid];

    const int eloc = wv * 16 + l15;
    const int r = r0 + eloc;
    const bool rvalid = (r < NR_);
    const int rc = rvalid ? r : NR_ - 1;      // clamped (invalid rows zeroed at fr3)

    // ---- phase A: Orr/Ors via MFMA; wave wv owns e-tile wv ----
    {
        Frag xh, xl;
        xh.v = ((const short8_t*)xAh)[b * 64 + lane];
        xl.v = ((const short8_t*)xAl)[b * 64 + lane];

        float vr[8], vs[8];
        #pragma unroll
        for (int j = 0; j < 8; ++j) {
            int n = q * 8 + j;
            vr[j] = (n < N_) ? RR[(b * N_ + n) * NR_ + rc] : 0.f;
            vs[j] = (n < N_) ? RS[(b * N_ + n) * NR_ + rc] : 0.f;
        }
        Frag rrh, rrl, rsh, rsl;
        #pragma unroll
        for (int d0 = 0; d0 < 4; ++d0) {
            split2(vr[2*d0], vr[2*d0+1], rrh.d[d0], rrl.d[d0]);
            split2(vs[2*d0], vs[2*d0+1], rsh.d[d0], rsl.d[d0]);
        }

        f32x4 aR = {0.f,0.f,0.f,0.f}, aS = {0.f,0.f,0.f,0.f};
        aR = mfma(xh.v, rrh.v, aR); aR = mfma(xl.v, rrh.v, aR); aR = mfma(xh.v, rrl.v, aR);
        aS = mfma(xh.v, rsh.v, aS); aS = mfma(xl.v, rsh.v, aS); aS = mfma(xh.v, rsl.v, aS);

        unsigned int h01, h23, l01, l23;
        split2(aR[0], aR[1], h01, l01); split2(aR[2], aR[3], h23, l23);
        { uint2 hh = {h01, h23}, ll = {l01, l23};
          *(uint2*)&aT[0][eloc][q * 4] = hh;
          *(uint2*)&aT[1][eloc][q * 4] = ll; }
        split2(aS[0], aS[1], h01, l01); split2(aS[2], aS[3], h23, l23);
        { uint2 hh = {h01, h23}, ll = {l01, l23};
          *(uint2*)&aT[0][eloc][16 + q * 4] = hh;
          *(uint2*)&aT[1][eloc][16 + q * 4] = ll; }

        if (q < DR_)
            raT[eloc][q] = rvalid ? RA[(b * DR_ + q) * NR_ + r] : 0.f;
    }
    __syncthreads();                                      // S2

    // ---- fr1/fr2 halves: fr1 half hf -> h1T; fr2 partial into registers ----
    short8_t W2hf[4], W2lf[4];
    #pragma unroll
    for (int kt = 0; kt < 4; ++kt) {
        W2hf[kt] = ((const short8_t*)w2h)[(wv * 4 + kt) * 64 + lane];
        W2lf[kt] = ((const short8_t*)w2l)[(wv * 4 + kt) * 64 + lane];
    }
    f32x4 acc2[4];
    #pragma unroll
    for (int et = 0; et < 4; ++et) acc2[et] = (f32x4){0.f,0.f,0.f,0.f};

    #pragma unroll
    for (int hf = 0; hf < 2; ++hf) {
        // fr1: wave owns mt = hf*4 + wv; K-tile kt=0 only; RA part in f32 VALU
        {
            const int mt = hf * 4 + wv;
            short8_t W1h0 = ((const short8_t*)w1h)[(mt * 2 + 0) * 64 + lane];
            short8_t W1l0 = ((const short8_t*)w1l)[(mt * 2 + 0) * 64 + lane];
            float w1c[4][3];
            #pragma unroll
            for (int c = 0; c < 4; ++c) {
                int row = mt * 16 + q * 4 + c;
                w1c[c][0] = w1f[row * 35 + 32];
                w1c[c][1] = w1f[row * 35 + 33];
                w1c[c][2] = w1f[row * 35 + 34];
            }
            #pragma unroll
            for (int et = 0; et < 4; ++et) {
                int e = et * 16 + l15;
                f32x4 acc = {0.f,0.f,0.f,0.f};
                short8_t Bh = *(const short8_t*)&aT[0][e][q * 8];
                short8_t Bl = *(const short8_t*)&aT[1][e][q * 8];
                acc = mfma(W1h0, Bh, acc);
                acc = mfma(W1l0, Bh, acc);
                acc = mfma(W1h0, Bl, acc);
                float ra0 = raT[e][0], ra1 = raT[e][1], ra2 = raT[e][2];
                float hv0 = fmaxf(acc[0] + b1s[mt*16 + q*4 + 0]
                                  + w1c[0][0]*ra0 + w1c[0][1]*ra1 + w1c[0][2]*ra2, 0.f);
                float hv1 = fmaxf(acc[1] + b1s[mt*16 + q*4 + 1]
                                  + w1c[1][0]*ra0 + w1c[1][1]*ra1 + w1c[1][2]*ra2, 0.f);
                float hv2 = fmaxf(acc[2] + b1s[mt*16 + q*4 + 2]
                                  + w1c[2][0]*ra0 + w1c[2][1]*ra1 + w1c[2][2]*ra2, 0.f);
                float hv3 = fmaxf(acc[3] + b1s[mt*16 + q*4 + 3]
                                  + w1c[3][0]*ra0 + w1c[3][1]*ra1 + w1c[3][2]*ra2, 0.f);
                unsigned int d01, d23, e01, e23;
                split2(hv0, hv1, d01, e01); split2(hv2, hv3, d23, e23);
                uint2 hh = {d01, d23}, ll = {e01, e23};
                *(uint2*)&u2.h1T[0][e][wv * 16 + q * 4] = hh;
                *(uint2*)&u2.h1T[1][e][wv * 16 + q * 4] = ll;
            }
        }
        __syncthreads();                                  // S3 / S5

        // fr2 partial: K-tiles kt = hf*2 + {0,1}
        #pragma unroll
        for (int et = 0; et < 4; ++et) {
            int e = et * 16 + l15;
            #pragma unroll
            for (int ktl = 0; ktl < 2; ++ktl) {
                short8_t bh = *(const short8_t*)&u2.h1T[0][e][ktl * 32 + q * 8];
                short8_t bl = *(const short8_t*)&u2.h1T[1][e][ktl * 32 + q * 8];
                acc2[et] = mfma(W2hf[hf * 2 + ktl], bh, acc2[et]);
                acc2[et] = mfma(W2lf[hf * 2 + ktl], bh, acc2[et]);
                acc2[et] = mfma(W2hf[hf * 2 + ktl], bl, acc2[et]);
            }
        }
        if (hf == 1) {
            __syncthreads();                              // S5b (h1T dead -> h2T)
            #pragma unroll
            for (int et = 0; et < 4; ++et) {
                int e = et * 16 + l15;
                float4 st;
                st.x = fmaxf(acc2[et][0] + b2s[wv * 16 + q * 4 + 0], 0.f);
                st.y = fmaxf(acc2[et][1] + b2s[wv * 16 + q * 4 + 1], 0.f);
                st.z = fmaxf(acc2[et][2] + b2s[wv * 16 + q * 4 + 2], 0.f);
                st.w = fmaxf(acc2[et][3] + b2s[wv * 16 + q * 4 + 3], 0.f);
                *(float4*)&u2.h2T[e][wv * 16 + q * 4] = st;
            }
        }
        __syncthreads();                                  // S4 / S6
    }

    // ---- fr3 (64 -> 5), VALU; w3/b3 from global (L2-hot) ----
    for (int it = tid; it < 64 * DE_; it += 256) {
        int e = it / DE_, i = it - e * DE_;
        float s = b3[i];
        const float* wr = w3 + i * 64;
        #pragma unroll
        for (int k = 0; k < 64; k += 4) {
            float4 hv = *(const float4*)&u2.h2T[e][k];
            float4 wv4 = *(const float4*)&wr[k];
            s += hv.x * wv4.x + hv.y * wv4.y + hv.z * wv4.z + hv.w * wv4.w;
        }
        Ee[e][i] = ((r0 + e) < NR_) ? fmaxf(s, 0.f) : 0.f;
    }
    __syncthreads();                                      // S7

    // ---- Ebar[b][i][n] += sum_e Ee[e][i] * RR[n][r0+e] (RR L2-hot) ----
    if (tid < DE_ * N_) {
        int i = tid / N_, n = tid - i * N_;
        const float* pr = &RR[(b * N_ + n) * NR_ + r0];
        const int emax = (NR_ - r0 < 64) ? (NR_ - r0) : 64;
        float s = 0.f;
        for (int e = 0; e < emax; ++e) s += Ee[e][i] * pr[e];
        atomicAdd(&Ebar[(b * DE_ + i) * N_ + n], s);
    }
}

// ---------------------------------------------------------------------------
// k_nodef v2b: fused node+final MLP, 1 batch/block (1024 blocks), LDS 32.6 KB.
// Plain launch bounds (no VGPR clamp).
// ---------------------------------------------------------------------------
__global__ __launch_bounds__(256) void k_nodef(
    const float* __restrict__ x, const float* __restrict__ Ebar,
    const float* __restrict__ bo1, const float* __restrict__ bo2,
    const float* __restrict__ wo3, const float* __restrict__ bo3,
    const ushort_t* __restrict__ wo1h, const ushort_t* __restrict__ wo1l,
    const ushort_t* __restrict__ wo2h, const ushort_t* __restrict__ wo2l,
    const float* __restrict__ wc1, const float* __restrict__ bc1,
    const float* __restrict__ wc2, const float* __restrict__ bc2,
    const float* __restrict__ wc3, const float* __restrict__ bc3,
    float* __restrict__ out)
{
    const int b = blockIdx.x;
    const int tid = threadIdx.x;
    const int lane = tid & 63;
    const int wv = tid >> 6;
    const int l15 = lane & 15;
    const int q = lane >> 4;

    __shared__ union {                      // 5120 B (cT dead before f used)
        ushort_t cT[2][32][40];
        struct { float fs[192]; float h1s[128]; float h2s[64]; } f;
    } u;
    __shared__ ushort_t h1T[2][32][136];    // 17408 B
    __shared__ float h2T[32][68];           // 8704 B
    __shared__ float b1s[128], b2s[64];     // 768 B

    if (tid < 128) b1s[tid] = bo1[tid];
    if (tid < 64)  b2s[tid] = bo2[tid];

    for (int idx = tid; idx < 32 * 32; idx += 256) {
        int c = idx >> 5, k = idx & 31;
        float v = 0.f;
        if (c < N_) {
            if (k < 16)      v = x[(b * N_ + c) * P_ + k];
            else if (k < 21) v = Ebar[(b * DE_ + (k - 16)) * N_ + c];
        }
        ushort_t h_, l_; split(v, h_, l_);
        u.cT[0][c][k] = h_; u.cT[1][c][k] = l_;
    }
    __syncthreads();

    {   // fo1: wave wv owns mt in {wv, wv+4}; 2 et tiles
        short8_t Wh[2], Wl[2];
        #pragma unroll
        for (int mi = 0; mi < 2; ++mi) {
            int mt = wv + mi * 4;
            Wh[mi] = ((const short8_t*)wo1h)[mt * 64 + lane];
            Wl[mi] = ((const short8_t*)wo1l)[mt * 64 + lane];
        }
        #pragma unroll
        for (int et = 0; et < 2; ++et) {
            int c = et * 16 + l15;
            short8_t bh = *(const short8_t*)&u.cT[0][c][q * 8];
            short8_t bl = *(const short8_t*)&u.cT[1][c][q * 8];
            #pragma unroll
            for (int mi = 0; mi < 2; ++mi) {
                int mt = wv + mi * 4;
                f32x4 acc = {0.f,0.f,0.f,0.f};
                acc = mfma(Wh[mi], bh, acc);
                acc = mfma(Wl[mi], bh, acc);
                acc = mfma(Wh[mi], bl, acc);
                float hv0 = fmaxf(acc[0] + b1s[mt * 16 + q * 4 + 0], 0.f);
                float hv1 = fmaxf(acc[1] + b1s[mt * 16 + q * 4 + 1], 0.f);
                float hv2 = fmaxf(acc[2] + b1s[mt * 16 + q * 4 + 2], 0.f);
                float hv3 = fmaxf(acc[3] + b1s[mt * 16 + q * 4 + 3], 0.f);
                unsigned int d01, d23, e01, e23;
                split2(hv0, hv1, d01, e01); split2(hv2, hv3, d23, e23);
                uint2 hh = {d01, d23}, ll = {e01, e23};
                *(uint2*)&h1T[0][c][mt * 16 + q * 4] = hh;
                *(uint2*)&h1T[1][c][mt * 16 + q * 4] = ll;
            }
        }
    }
    __syncthreads();

    {   // fo2: wave wv owns rows wv*16..wv*16+15, K=128 (4 kt)
        short8_t Wh[4], Wl[4];
        #pragma unroll
        for (int kt = 0; kt < 4; ++kt) {
            Wh[kt] = ((const short8_t*)wo2h)[(wv * 4 + kt) * 64 + lane];
            Wl[kt] = ((const short8_t*)wo2l)[(wv * 4 + kt) * 64 + lane];
        }
        #pragma unroll
        for (int et = 0; et < 2; ++et) {
            int c = et * 16 + l15;
            f32x4 acc = {0.f,0.f,0.f,0.f};
            #pragma unroll
            for (int kt = 0; kt < 4; ++kt) {
                short8_t bh = *(const short8_t*)&h1T[0][c][kt * 32 + q * 8];
                short8_t bl = *(const short8_t*)&h1T[1][c][kt * 32 + q * 8];
                acc = mfma(Wh[kt], bh, acc);
                acc = mfma(Wl[kt], bh, acc);
                acc = mfma(Wh[kt], bl, acc);
            }
            float4 st;
            st.x = fmaxf(acc[0] + b2s[wv * 16 + q * 4 + 0], 0.f);
            st.y = fmaxf(acc[1] + b2s[wv * 16 + q * 4 + 1], 0.f);
            st.z = fmaxf(acc[2] + b2s[wv * 16 + q * 4 + 2], 0.f);
            st.w = fmaxf(acc[3] + b2s[wv * 16 + q * 4 + 3], 0.f);
            *(float4*)&h2T[c][wv * 16 + q * 4] = st;
        }
    }
    __syncthreads();

    // fo3 -> fs (cT dead; union reuse)
    if (tid < N_ * DO_ + 12) {   // 192 threads
        int c = tid / DO_, i = tid - c * DO_;
        if (c < N_) {
            float s = bo3[i];
            const float* wr = wo3 + i * 64;
            #pragma unroll
            for (int k = 0; k < 64; k += 4) {
                float4 hv = *(const float4*)&h2T[c][k];
                float4 wv4 = *(const float4*)&wr[k];
                s += hv.x * wv4.x + hv.y * wv4.y + hv.z * wv4.z + hv.w * wv4.w;
            }
            u.f.fs[c * DO_ + i] = fmaxf(s, 0.f);
        }
    }
    __syncthreads();

    // ---- final MLP (fp32 VALU) ----
    if (tid < 128) {
        const float* wr = wc1 + tid * 180;
        float s = bc1[tid];
        #pragma unroll 5
        for (int k = 0; k < 180; k += 4) {
            float4 wv4 = *(const float4*)&wr[k];
            s += u.f.fs[k] * wv4.x + u.f.fs[k + 1] * wv4.y
               + u.f.fs[k + 2] * wv4.z + u.f.fs[k + 3] * wv4.w;
        }
        u.f.h1s[tid] = fmaxf(s, 0.f);
    }
    __syncthreads();

    if (tid < 64) {
        const float* wr = wc2 + tid * 128;
        float s = bc2[tid];
        #pragma unroll 4
        for (int k = 0; k < 128; k += 4) {
            float4 wv4 = *(const float4*)&wr[k];
            s += u.f.h1s[k] * wv4.x + u.f.h1s[k + 1] * wv4.y
               + u.f.h1s[k + 2] * wv4.z + u.f.h1s[k + 3] * wv4.w;
        }
        u.f.h2s[tid] = fmaxf(s, 0.f);
    }
    __syncthreads();

    if (tid < NT_) {
        const float* wr = wc3 + tid * 64;
        float s = bc3[tid];
        #pragma unroll
        for (int k = 0; k < 64; k += 4) {
            float4 wv4 = *(const float4*)&wr[k];
            s += u.f.h2s[k] * wv4.x + u.f.h2s[k + 1] * wv4.y
               + u.f.h2s[k + 2] * wv4.z + u.f.h2s[k + 3] * wv4.w;
        }
        out[b * NT_ + tid] = s;
    }
}

extern "C" void kernel_launch(void* const* d_in, const int* in_sizes, int n_in,
                              void* d_out, int out_size, void* d_ws, size_t ws_size,
                              hipStream_t stream)
{
    const float* x    = (const float*)d_in[0];
    const float* RR   = (const float*)d_in[1];
    const float* RS   = (const float*)d_in[2];
    const float* RA   = (const float*)d_in[3];
    const float* fr1w = (const float*)d_in[4];
    const float* fr1b = (const float*)d_in[5];
    const float* fr2w = (const float*)d_in[6];
    const float* fr2b = (const float*)d_in[7];
    const float* fr3w = (const float*)d_in[8];
    const float* fr3b = (const float*)d_in[9];
    const float* fo1w = (const float*)d_in[10];
    const float* fo1b = (const float*)d_in[11];
    const float* fo2w = (const float*)d_in[12];
    const float* fo2b = (const float*)d_in[13];
    const float* fo3w = (const float*)d_in[14];
    const float* fo3b = (const float*)d_in[15];
    const float* fc1w = (const float*)d_in[16];
    const float* fc1b = (const float*)d_in[17];
    const float* fc2w = (const float*)d_in[18];
    const float* fc2b = (const float*)d_in[19];
    const float* fc3w = (const float*)d_in[20];
    const float* fc3b = (const float*)d_in[21];
    float* out = (float*)d_out;

    // ---- workspace map ----
    float* Ebar = (float*)d_ws;                       // 1024*5*30
    ushort_t* base = (ushort_t*)(Ebar + B_ * DE_ * N_);
    ushort_t* xAh  = base;             ushort_t* xAl  = xAh  + 1024 * 512;
    ushort_t* w1h  = xAl  + 1024*512;  ushort_t* w1l  = w1h  + 16 * 512;
    ushort_t* w2h  = w1l  + 16*512;    ushort_t* w2l  = w2h  + 16 * 512;
    ushort_t* wo1h = w2l  + 16*512;    ushort_t* wo1l = wo1h + 8 * 512;
    ushort_t* wo2h = wo1l + 8*512;     ushort_t* wo2l = wo2h + 16 * 512;

    hipMemsetAsync(Ebar, 0, (size_t)B_ * DE_ * N_ * sizeof(float), stream);

    k_prep<<<1028, 256, 0, stream>>>(x, fr1w, fr2w, fo1w, fo2w,
                                     xAh, xAl, w1h, w1l, w2h, w2l,
                                     wo1h, wo1l, wo2h, wo2l);

    dim3 g1(14, B_);   // 14 * 64 = 896 >= 870 edges
    k_edge<<<g1, 256, 0, stream>>>(RR, RS, RA, fr1w, fr1b, fr2b, fr3w, fr3b,
                                   xAh, xAl, w1h, w1l, w2h, w2l, Ebar);
    k_nodef<<<B_, 256, 0, stream>>>(x, Ebar, fo1b, fo2b, fo3w, fo3b,
                                    wo1h, wo1l, wo2h, wo2l,
                                    fc1w, fc1b, fc2w, fc2b, fc3w, fc3b, out);
}